// Round 7
// baseline (209.731 us; speedup 1.0000x reference)
//
#include <hip/hip_runtime.h>

#define SQ 2048
#define DM 1024
#define NH 16
#define HD 64

typedef __bf16 bf16x8 __attribute__((ext_vector_type(8)));
typedef float f32x4 __attribute__((ext_vector_type(4)));
typedef unsigned short u16;
typedef unsigned int u32;

// fp32 -> bf16 round-to-nearest-even (bulk convert pass)
__device__ __forceinline__ u16 f2b(float f) {
  union { float f; u32 u; } c; c.f = f;
  return (u16)((c.u + 0x7FFFu + ((c.u >> 16) & 1u)) >> 16);
}

// async global->LDS, 16B per lane; lds dest = wave-uniform base + lane*16
__device__ __forceinline__ void gll16(const void* g, void* l) {
  __builtin_amdgcn_global_load_lds(
      (const __attribute__((address_space(1))) void*)g,
      (__attribute__((address_space(3))) void*)l, 16, 0, 0);
}

// ---------------------------------------------------------------------------
// fp32 -> bf16 convert pass: X (4M elems) + Wq/Wk/Wv/Wo (1M each)
// ---------------------------------------------------------------------------
__global__ void __launch_bounds__(256) conv_bf16(
    const float* __restrict__ X,
    const float* __restrict__ Wq, const float* __restrict__ Wk,
    const float* __restrict__ Wv, const float* __restrict__ Wo,
    u16* __restrict__ Xb, u16* __restrict__ Wqb, u16* __restrict__ Wkb,
    u16* __restrict__ Wvb, u16* __restrict__ Wob) {
  const size_t e = ((size_t)blockIdx.x * 256 + threadIdx.x) * 8;
  const float* src; u16* dst; size_t rel;
  if (e < 4194304u)      { src = X;  dst = Xb;  rel = e; }
  else if (e < 5242880u) { src = Wq; dst = Wqb; rel = e - 4194304u; }
  else if (e < 6291456u) { src = Wk; dst = Wkb; rel = e - 5242880u; }
  else if (e < 7340032u) { src = Wv; dst = Wvb; rel = e - 6291456u; }
  else                   { src = Wo; dst = Wob; rel = e - 7340032u; }
  float4 a = *(const float4*)(src + rel);
  float4 b = *(const float4*)(src + rel + 4);
  union { u16 h[8]; uint4 v; } o;
  o.h[0] = f2b(a.x); o.h[1] = f2b(a.y); o.h[2] = f2b(a.z); o.h[3] = f2b(a.w);
  o.h[4] = f2b(b.x); o.h[5] = f2b(b.y); o.h[6] = f2b(b.z); o.h[7] = f2b(b.w);
  *(uint4*)(dst + rel) = o.v;
}

// ---------------------------------------------------------------------------
// m97-style 128x128 NT GEMM core, bf16 inputs, BK=32, global_load_lds staging,
// double-buffered LDS ([2][128][32] linear per operand), 2-phase schedule.
// ---------------------------------------------------------------------------
__device__ __forceinline__ void stage128(const u16* __restrict__ A, const u16* __restrict__ B,
                                         u16* sA, u16* sB, int m0, int n0, int kt,
                                         int w, int l) {
#pragma unroll
  for (int c = 0; c < 2; ++c) {
    const int g = w * 2 + c;       // chunk-group 0..7 (1 KB each)
    const int s = g * 64 + l;      // 16B slot 0..511
    const int r = s >> 2, cc = s & 3;
    gll16(A + (size_t)(m0 + r) * DM + kt * 32 + cc * 8, sA + g * 512);
    gll16(B + (size_t)(n0 + r) * DM + kt * 32 + cc * 8, sB + g * 512);
  }
}

__device__ __forceinline__ void gemm_core2(const u16* __restrict__ A, const u16* __restrict__ B,
                                           u16* sA, u16* sB,   // each [2][4096] u16
                                           int m0, int n0, f32x4 acc[4][4]) {
  const int t = threadIdx.x, l = t & 63, w = t >> 6;
  const int wr = w >> 1, wc = w & 1, lg = l >> 4, li = l & 15;

  stage128(A, B, sA, sB, m0, n0, 0, w, l);
  __syncthreads();  // drains vmcnt(0) before barrier
  int cur = 0;
  for (int kt = 0; kt < DM / 32; ++kt) {
    if (kt + 1 < DM / 32)
      stage128(A, B, sA + (cur ^ 1) * 4096, sB + (cur ^ 1) * 4096, m0, n0, kt + 1, w, l);
    bf16x8 aF[4], bF[4];
#pragma unroll
    for (int mi = 0; mi < 4; ++mi)
      aF[mi] = *(const bf16x8*)(sA + cur * 4096 + (wr * 64 + mi * 16 + li) * 32 + lg * 8);
#pragma unroll
    for (int ni = 0; ni < 4; ++ni)
      bF[ni] = *(const bf16x8*)(sB + cur * 4096 + (wc * 64 + ni * 16 + li) * 32 + lg * 8);
#pragma unroll
    for (int mi = 0; mi < 4; ++mi)
#pragma unroll
      for (int ni = 0; ni < 4; ++ni)
        acc[mi][ni] = __builtin_amdgcn_mfma_f32_16x16x32_bf16(aF[mi], bF[ni], acc[mi][ni], 0, 0, 0);
    __syncthreads();
    cur ^= 1;
  }
}

// ---------------------------------------------------------------------------
// QKV projection (bf16 in): z = 0:Q (scaled log2e/8), 1:K, 2:V^T ([bh][dd][s])
// ---------------------------------------------------------------------------
__global__ void __launch_bounds__(256) qkv_gemm(
    const u16* __restrict__ Xb,
    const u16* __restrict__ Wqb, const u16* __restrict__ Wkb, const u16* __restrict__ Wvb,
    const float* __restrict__ bq, const float* __restrict__ bk, const float* __restrict__ bv,
    u16* __restrict__ Qb, u16* __restrict__ Kb, u16* __restrict__ Vt) {
  __shared__ u16 sA[8192];
  __shared__ u16 sB[8192];
  const int mode = blockIdx.z;
  const u16* W = (mode == 0) ? Wqb : (mode == 1) ? Wkb : Wvb;
  const float* bias = (mode == 0) ? bq : (mode == 1) ? bk : bv;
  const int m0 = blockIdx.y * 128, n0 = blockIdx.x * 128;

  f32x4 acc[4][4];
  f32x4 z4 = {0.f, 0.f, 0.f, 0.f};
#pragma unroll
  for (int i = 0; i < 4; ++i)
#pragma unroll
    for (int j = 0; j < 4; ++j) acc[i][j] = z4;

  gemm_core2(Xb, W, sA, sB, m0, n0, acc);

  const int t = threadIdx.x;
  const int l = t & 63, w = t >> 6;
  const int wr = w >> 1, wc = w & 1, lg = l >> 4, li = l & 15;
#pragma unroll
  for (int mi = 0; mi < 4; ++mi) {
    const int m = m0 + wr * 64 + mi * 16 + lg * 4;
    const int b = m >> 11;           // batch
    const int s = m & 2047;          // seq pos
#pragma unroll
    for (int ni = 0; ni < 4; ++ni) {
      const int n = n0 + wc * 64 + ni * 16 + li;
      const int h = n >> 6, dd = n & 63;
      const float bia = bias[n];
      const size_t bh = (size_t)(b * NH + h);
#pragma unroll
      for (int r = 0; r < 4; ++r) {
        const float val = acc[mi][ni][r] + bia;
        const int ss = s + r;
        // Q prescale: (1/sqrt(HD)) * log2(e) so attn works in exp2 domain
        if (mode == 0)      Qb[(bh * SQ + ss) * HD + dd] = f2b(val * 0.180336880f);
        else if (mode == 1) Kb[(bh * SQ + ss) * HD + dd] = f2b(val);
        else                Vt[(bh * HD + dd) * SQ + ss] = f2b(val);
      }
    }
  }
}

// ---------------------------------------------------------------------------
// Final projection: out = Ao * Wo^T + bo (bf16 in, fp32 out)
// ---------------------------------------------------------------------------
__global__ void __launch_bounds__(256) out_gemm(
    const u16* __restrict__ Ag, const u16* __restrict__ Wob,
    const float* __restrict__ bo, float* __restrict__ out) {
  __shared__ u16 sA[8192];
  __shared__ u16 sB[8192];
  const int m0 = blockIdx.y * 128, n0 = blockIdx.x * 128;

  f32x4 acc[4][4];
  f32x4 z4 = {0.f, 0.f, 0.f, 0.f};
#pragma unroll
  for (int i = 0; i < 4; ++i)
#pragma unroll
    for (int j = 0; j < 4; ++j) acc[i][j] = z4;

  gemm_core2(Ag, Wob, sA, sB, m0, n0, acc);

  const int t = threadIdx.x;
  const int l = t & 63, w = t >> 6;
  const int wr = w >> 1, wc = w & 1, lg = l >> 4, li = l & 15;
#pragma unroll
  for (int mi = 0; mi < 4; ++mi) {
    const int m = m0 + wr * 64 + mi * 16 + lg * 4;
#pragma unroll
    for (int ni = 0; ni < 4; ++ni) {
      const int n = n0 + wc * 64 + ni * 16 + li;
      const float bia = bo[n];
#pragma unroll
      for (int r = 0; r < 4; ++r)
        out[(size_t)(m + r) * DM + n] = acc[mi][ni][r] + bia;
    }
  }
}

// ---------------------------------------------------------------------------
// Flash attention v7: occupancy fix. 16 queries/wave, 4 waves/block,
// grid (bh=32, qt=32) = 1024 blocks = 4 blocks/CU = 50% occupancy cap
// (v4/v6 were capped at 25% -> MfmaUtil plateaued ~21%).
//  - MFMA stays 100% payload-dense (16 q fills the B-operand exactly)
//  - K sigma-staged LDS dbuf shared by 4 waves (zero-shuffle P->PV)
//  - V direct from global, issued at tile top (covered by QK+exp2)
//  - fixed-anchor exp2 softmax; masked queries via qf=0
//  - l on VALU, computed AFTER PV issue (off both MFMA pipe and crit path)
// ---------------------------------------------------------------------------
__global__ void __launch_bounds__(256) attn_v7(
    const u16* __restrict__ Qb, const u16* __restrict__ Kb, const u16* __restrict__ Vt,
    const int* __restrict__ vlen, u16* __restrict__ Ao) {
  __shared__ u16 sK[2][4096];   // [64 keys(sigma)][64 dk], chunk-XOR swizzled
  const int bh = blockIdx.x, qt = blockIdx.y;
  const int t = threadIdx.x, w = t >> 6, l = t & 63, lg = l >> 4, li = l & 15;
  const int vl = vlen[bh];
  const u16* Qh = Qb + (size_t)bh * SQ * HD;
  const u16* Kh = Kb + (size_t)bh * SQ * HD;
  const u16* Vh = Vt + (size_t)bh * HD * SQ;
  const int q0 = qt * 64 + w * 16;        // this wave's 16 queries: q0 + li

  // Q fragment, masked queries zeroed (uniform softmax == reference row-mask)
  const bool mq = (q0 + li) >= vl;
  bf16x8 qf[2];
#pragma unroll
  for (int kk = 0; kk < 2; ++kk) {
    qf[kk] = *(const bf16x8*)(Qh + (size_t)(q0 + li) * HD + kk * 32 + lg * 8);
    if (mq) {
      union { u32 u[4]; bf16x8 v; } z; z.u[0] = z.u[1] = z.u[2] = z.u[3] = 0;
      qf[kk] = z.v;
    }
  }

  // K staging geometry: 8 x 1KB chunks, 2 per wave; sigma row permute +
  // chunk-XOR swizzle folded into the per-lane GLOBAL source offset
  int gq[2], kOff[2];
#pragma unroll
  for (int c = 0; c < 2; ++c) {
    gq[c] = w * 2 + c;
    const int s = gq[c] * 64 + l;      // 16B slot 0..511
    const int r = s >> 3, cs = s & 7;
    const int csrc = cs ^ (r & 7);
    const int sig = (r & 32) | (((r >> 2) & 3) << 3) | (((r >> 4) & 1) << 2) | (r & 3);
    kOff[c] = sig * HD + csrc * 8;
  }
  auto stageK = [&](int buf, int kt) {
#pragma unroll
    for (int c = 0; c < 2; ++c)
      gll16(Kh + (size_t)(kt * 64) * HD + kOff[c], &sK[buf][gq[c] * 512]);
  };

  f32x4 z4 = {0.f, 0.f, 0.f, 0.f};
  f32x4 acc[4];
#pragma unroll
  for (int ni = 0; ni < 4; ++ni) acc[ni] = z4;
  float l_r = 0.f;

  stageK(0, 0);
  __syncthreads();
  int cur = 0;
  for (int kt = 0; kt < SQ / 64; ++kt) {
    // V loads issued first (consumed after QK+exp2 ~400cyc later);
    // identical rows across the 4 waves -> L1/L2 sharing
    bf16x8 vf[4][2];
#pragma unroll
    for (int ni = 0; ni < 4; ++ni) {
      const u16* vrow = Vh + (size_t)(ni * 16 + li) * SQ + kt * 64 + lg * 8;
      vf[ni][0] = *(const bf16x8*)(vrow);
      vf[ni][1] = *(const bf16x8*)(vrow + 32);
    }
    if (kt + 1 < SQ / 64) stageK(cur ^ 1, kt + 1);

    // S^T = K Q^T (log2 domain)
    f32x4 sc[4];
#pragma unroll
    for (int ni = 0; ni < 4; ++ni) {
      const int row = ni * 16 + li;
      bf16x8 kf0 = *(const bf16x8*)(&sK[cur][row * 64 + ((lg ^ (row & 7)) * 8)]);
      bf16x8 kf1 = *(const bf16x8*)(&sK[cur][row * 64 + (((4 + lg) ^ (row & 7)) * 8)]);
      sc[ni] = __builtin_amdgcn_mfma_f32_16x16x32_bf16(kf0, qf[0], z4, 0, 0, 0);
      sc[ni] = __builtin_amdgcn_mfma_f32_16x16x32_bf16(kf1, qf[1], sc[ni], 0, 0, 0);
    }

    // fixed-anchor softmax: p = exp2(sc), packed straight into PV B-frags
    float p[4][4];
#pragma unroll
    for (int ni = 0; ni < 4; ++ni)
#pragma unroll
      for (int j = 0; j < 4; ++j)
        p[ni][j] = __builtin_amdgcn_exp2f(sc[ni][j]);

    bf16x8 pb[2];
#pragma unroll
    for (int h = 0; h < 2; ++h) {
      union { __bf16 e[8]; bf16x8 v; } P;
#pragma unroll
      for (int j = 0; j < 4; ++j) {
        P.e[j]     = (__bf16)p[2 * h][j];
        P.e[4 + j] = (__bf16)p[2 * h + 1][j];
      }
      pb[h] = P.v;
    }

    // O^T += V^T P^T
#pragma unroll
    for (int ni = 0; ni < 4; ++ni) {
      acc[ni] = __builtin_amdgcn_mfma_f32_16x16x32_bf16(vf[ni][0], pb[0], acc[ni], 0, 0, 0);
      acc[ni] = __builtin_amdgcn_mfma_f32_16x16x32_bf16(vf[ni][1], pb[1], acc[ni], 0, 0, 0);
    }

    // l partial on VALU, off the critical path (only needed at epilogue)
    l_r += ((p[0][0] + p[0][1]) + (p[0][2] + p[0][3]))
         + ((p[1][0] + p[1][1]) + (p[1][2] + p[1][3]))
         + ((p[2][0] + p[2][1]) + (p[2][2] + p[2][3]))
         + ((p[3][0] + p[3][1]) + (p[3][2] + p[3][3]));

    __syncthreads();
    cur ^= 1;
  }

  // epilogue: reduce l across the 4 lane-groups (each holds 16 of 64 keys)
  float lf = l_r;
  lf += __shfl_xor(lf, 16);
  lf += __shfl_xor(lf, 32);
  const float inv = 1.0f / lf;

  const int b = bh >> 4, h = bh & 15;
  const size_t rowb = ((size_t)(b * SQ + q0 + li)) * DM + h * HD;
#pragma unroll
  for (int ni = 0; ni < 4; ++ni) {
    union { __bf16 h2[4]; uint2 u; } ov;
#pragma unroll
    for (int r = 0; r < 4; ++r) ov.h2[r] = (__bf16)(acc[ni][r] * inv);
    *(uint2*)(Ao + rowb + ni * 16 + lg * 4) = ov.u;
  }
}

extern "C" void kernel_launch(void* const* d_in, const int* in_sizes, int n_in,
                              void* d_out, int out_size, void* d_ws, size_t ws_size,
                              hipStream_t stream) {
  const float* X  = (const float*)d_in[0];
  const float* Wq = (const float*)d_in[1];
  const float* bq = (const float*)d_in[2];
  const float* Wk = (const float*)d_in[3];
  const float* bk = (const float*)d_in[4];
  const float* Wv = (const float*)d_in[5];
  const float* bv = (const float*)d_in[6];
  const float* Wo = (const float*)d_in[7];
  const float* bo = (const float*)d_in[8];
  const int* vlen = (const int*)d_in[9];

  char* ws = (char*)d_ws;
  u16* Qb  = (u16*)(ws);                       // 8 MB [32][2048][64]
  u16* Kb  = (u16*)(ws + (size_t)8388608);     // 8 MB
  u16* Vt  = (u16*)(ws + (size_t)16777216);    // 8 MB [32][64][2048]
  u16* Xb  = (u16*)(ws + (size_t)25165824);    // 8 MB [4096][1024] bf16
  u16* Ao  = Xb;                               // alias: Xb dead after qkv_gemm
  u16* Wqb = (u16*)(ws + (size_t)33554432);    // 2 MB each
  u16* Wkb = (u16*)(ws + (size_t)35651584);
  u16* Wvb = (u16*)(ws + (size_t)37748736);
  u16* Wob = (u16*)(ws + (size_t)39845888);    // ends at 40 MB

  dim3 blk(256);
  conv_bf16<<<4096, blk, 0, stream>>>(X, Wq, Wk, Wv, Wo, Xb, Wqb, Wkb, Wvb, Wob);
  qkv_gemm<<<dim3(8, 32, 3), blk, 0, stream>>>(Xb, Wqb, Wkb, Wvb, bq, bk, bv, Qb, Kb, Vt);
  attn_v7<<<dim3(32, 32), blk, 0, stream>>>(Qb, Kb, Vt, vlen, Ao);
  out_gemm<<<dim3(8, 32), blk, 0, stream>>>(Ao, Wob, bo, (float*)d_out);
}

// Round 8
// 127.711 us; speedup vs baseline: 1.6422x; 1.6422x over previous
//
#include <hip/hip_runtime.h>

#define SQ 2048
#define DM 1024
#define NH 16
#define HD 64

typedef __bf16 bf16x8 __attribute__((ext_vector_type(8)));
typedef float f32x4 __attribute__((ext_vector_type(4)));
typedef unsigned short u16;
typedef unsigned int u32;

// fp32 -> bf16 round-to-nearest-even (bulk convert pass)
__device__ __forceinline__ u16 f2b(float f) {
  union { float f; u32 u; } c; c.f = f;
  return (u16)((c.u + 0x7FFFu + ((c.u >> 16) & 1u)) >> 16);
}

// async global->LDS, 16B per lane; lds dest = wave-uniform base + lane*16
__device__ __forceinline__ void gll16(const void* g, void* l) {
  __builtin_amdgcn_global_load_lds(
      (const __attribute__((address_space(1))) void*)g,
      (__attribute__((address_space(3))) void*)l, 16, 0, 0);
}

// ---------------------------------------------------------------------------
// fp32 -> bf16 convert pass: X (4M elems) + Wq/Wk/Wv/Wo (1M each)
// ---------------------------------------------------------------------------
__global__ void __launch_bounds__(256) conv_bf16(
    const float* __restrict__ X,
    const float* __restrict__ Wq, const float* __restrict__ Wk,
    const float* __restrict__ Wv, const float* __restrict__ Wo,
    u16* __restrict__ Xb, u16* __restrict__ Wqb, u16* __restrict__ Wkb,
    u16* __restrict__ Wvb, u16* __restrict__ Wob) {
  const size_t e = ((size_t)blockIdx.x * 256 + threadIdx.x) * 8;
  const float* src; u16* dst; size_t rel;
  if (e < 4194304u)      { src = X;  dst = Xb;  rel = e; }
  else if (e < 5242880u) { src = Wq; dst = Wqb; rel = e - 4194304u; }
  else if (e < 6291456u) { src = Wk; dst = Wkb; rel = e - 5242880u; }
  else if (e < 7340032u) { src = Wv; dst = Wvb; rel = e - 6291456u; }
  else                   { src = Wo; dst = Wob; rel = e - 7340032u; }
  float4 a = *(const float4*)(src + rel);
  float4 b = *(const float4*)(src + rel + 4);
  union { u16 h[8]; uint4 v; } o;
  o.h[0] = f2b(a.x); o.h[1] = f2b(a.y); o.h[2] = f2b(a.z); o.h[3] = f2b(a.w);
  o.h[4] = f2b(b.x); o.h[5] = f2b(b.y); o.h[6] = f2b(b.z); o.h[7] = f2b(b.w);
  *(uint4*)(dst + rel) = o.v;
}

// ---------------------------------------------------------------------------
// m97-style 128x128 NT GEMM core, bf16 inputs, BK=32, global_load_lds staging,
// double-buffered LDS ([2][128][32] linear per operand), 2-phase schedule.
// ---------------------------------------------------------------------------
__device__ __forceinline__ void stage128(const u16* __restrict__ A, const u16* __restrict__ B,
                                         u16* sA, u16* sB, int m0, int n0, int kt,
                                         int w, int l) {
#pragma unroll
  for (int c = 0; c < 2; ++c) {
    const int g = w * 2 + c;       // chunk-group 0..7 (1 KB each)
    const int s = g * 64 + l;      // 16B slot 0..511
    const int r = s >> 2, cc = s & 3;
    gll16(A + (size_t)(m0 + r) * DM + kt * 32 + cc * 8, sA + g * 512);
    gll16(B + (size_t)(n0 + r) * DM + kt * 32 + cc * 8, sB + g * 512);
  }
}

__device__ __forceinline__ void gemm_core2(const u16* __restrict__ A, const u16* __restrict__ B,
                                           u16* sA, u16* sB,   // each [2][4096] u16
                                           int m0, int n0, f32x4 acc[4][4]) {
  const int t = threadIdx.x, l = t & 63, w = t >> 6;
  const int wr = w >> 1, wc = w & 1, lg = l >> 4, li = l & 15;

  stage128(A, B, sA, sB, m0, n0, 0, w, l);
  __syncthreads();  // drains vmcnt(0) before barrier
  int cur = 0;
  for (int kt = 0; kt < DM / 32; ++kt) {
    if (kt + 1 < DM / 32)
      stage128(A, B, sA + (cur ^ 1) * 4096, sB + (cur ^ 1) * 4096, m0, n0, kt + 1, w, l);
    bf16x8 aF[4], bF[4];
#pragma unroll
    for (int mi = 0; mi < 4; ++mi)
      aF[mi] = *(const bf16x8*)(sA + cur * 4096 + (wr * 64 + mi * 16 + li) * 32 + lg * 8);
#pragma unroll
    for (int ni = 0; ni < 4; ++ni)
      bF[ni] = *(const bf16x8*)(sB + cur * 4096 + (wc * 64 + ni * 16 + li) * 32 + lg * 8);
#pragma unroll
    for (int mi = 0; mi < 4; ++mi)
#pragma unroll
      for (int ni = 0; ni < 4; ++ni)
        acc[mi][ni] = __builtin_amdgcn_mfma_f32_16x16x32_bf16(aF[mi], bF[ni], acc[mi][ni], 0, 0, 0);
    __syncthreads();
    cur ^= 1;
  }
}

// ---------------------------------------------------------------------------
// QKV projection (bf16 in): z = 0:Q (scaled log2e/8), 1:K, 2:V^T ([bh][dd][s])
// ---------------------------------------------------------------------------
__global__ void __launch_bounds__(256) qkv_gemm(
    const u16* __restrict__ Xb,
    const u16* __restrict__ Wqb, const u16* __restrict__ Wkb, const u16* __restrict__ Wvb,
    const float* __restrict__ bq, const float* __restrict__ bk, const float* __restrict__ bv,
    u16* __restrict__ Qb, u16* __restrict__ Kb, u16* __restrict__ Vt) {
  __shared__ u16 sA[8192];
  __shared__ u16 sB[8192];
  const int mode = blockIdx.z;
  const u16* W = (mode == 0) ? Wqb : (mode == 1) ? Wkb : Wvb;
  const float* bias = (mode == 0) ? bq : (mode == 1) ? bk : bv;
  const int m0 = blockIdx.y * 128, n0 = blockIdx.x * 128;

  f32x4 acc[4][4];
  f32x4 z4 = {0.f, 0.f, 0.f, 0.f};
#pragma unroll
  for (int i = 0; i < 4; ++i)
#pragma unroll
    for (int j = 0; j < 4; ++j) acc[i][j] = z4;

  gemm_core2(Xb, W, sA, sB, m0, n0, acc);

  const int t = threadIdx.x;
  const int l = t & 63, w = t >> 6;
  const int wr = w >> 1, wc = w & 1, lg = l >> 4, li = l & 15;
#pragma unroll
  for (int mi = 0; mi < 4; ++mi) {
    const int m = m0 + wr * 64 + mi * 16 + lg * 4;
    const int b = m >> 11;           // batch
    const int s = m & 2047;          // seq pos
#pragma unroll
    for (int ni = 0; ni < 4; ++ni) {
      const int n = n0 + wc * 64 + ni * 16 + li;
      const int h = n >> 6, dd = n & 63;
      const float bia = bias[n];
      const size_t bh = (size_t)(b * NH + h);
#pragma unroll
      for (int r = 0; r < 4; ++r) {
        const float val = acc[mi][ni][r] + bia;
        const int ss = s + r;
        // Q prescale: (1/sqrt(HD)) * log2(e) so attn works in exp2 domain
        if (mode == 0)      Qb[(bh * SQ + ss) * HD + dd] = f2b(val * 0.180336880f);
        else if (mode == 1) Kb[(bh * SQ + ss) * HD + dd] = f2b(val);
        else                Vt[(bh * HD + dd) * SQ + ss] = f2b(val);
      }
    }
  }
}

// ---------------------------------------------------------------------------
// Final projection: out = Ao * Wo^T + bo (bf16 in, fp32 out)
// ---------------------------------------------------------------------------
__global__ void __launch_bounds__(256) out_gemm(
    const u16* __restrict__ Ag, const u16* __restrict__ Wob,
    const float* __restrict__ bo, float* __restrict__ out) {
  __shared__ u16 sA[8192];
  __shared__ u16 sB[8192];
  const int m0 = blockIdx.y * 128, n0 = blockIdx.x * 128;

  f32x4 acc[4][4];
  f32x4 z4 = {0.f, 0.f, 0.f, 0.f};
#pragma unroll
  for (int i = 0; i < 4; ++i)
#pragma unroll
    for (int j = 0; j < 4; ++j) acc[i][j] = z4;

  gemm_core2(Ag, Wob, sA, sB, m0, n0, acc);

  const int t = threadIdx.x;
  const int l = t & 63, w = t >> 6;
  const int wr = w >> 1, wc = w & 1, lg = l >> 4, li = l & 15;
#pragma unroll
  for (int mi = 0; mi < 4; ++mi) {
    const int m = m0 + wr * 64 + mi * 16 + lg * 4;
#pragma unroll
    for (int ni = 0; ni < 4; ++ni) {
      const int n = n0 + wc * 64 + ni * 16 + li;
      const float bia = bo[n];
#pragma unroll
      for (int r = 0; r < 4; ++r)
        out[(size_t)(m + r) * DM + n] = acc[mi][ni][r] + bia;
    }
  }
}

// ---------------------------------------------------------------------------
// Flash attention v8 = v6 + V staged in LDS (the v4 pipeline shape):
//  - 4 waves x 32 queries, K sigma-staged + V^T staged, both gll16 dbuf
//    (prefetched a full tile ahead; barrier drain guarantees arrival)
//  - zero-shuffle P->PV (sigma'd K keys == natural V keys, index-verified)
//  - fixed-anchor log2 softmax: p = exp2(sc); masked queries via qf=0
//  - l via ones-MFMA (idle matrix pipe, no VALU reduction, no shfl)
//  - bh-fastest grid: id%8 = bh%8 pins 4 heads' K/V (2MB) per XCD L2
// ---------------------------------------------------------------------------
__global__ void __launch_bounds__(256) attn_v8(
    const u16* __restrict__ Qb, const u16* __restrict__ Kb, const u16* __restrict__ Vt,
    const int* __restrict__ vlen, u16* __restrict__ Ao) {
  __shared__ u16 sK[2][4096];   // [64 keys(sigma)][64 dk], chunk-XOR swizzled
  __shared__ u16 sV[2][4096];   // [64 d][64 keys(natural)], chunk-XOR swizzled
  const int bh = blockIdx.x, qt = blockIdx.y;
  const int t = threadIdx.x, w = t >> 6, l = t & 63, lg = l >> 4, li = l & 15;
  const int vl = vlen[bh];
  const u16* Qh = Qb + (size_t)bh * SQ * HD;
  const u16* Kh = Kb + (size_t)bh * SQ * HD;
  const u16* Vh = Vt + (size_t)bh * HD * SQ;
  const int q0w = qt * 128 + w * 32;      // wave's 32 queries: q0w + g*16 + li

  // Q fragments, masked queries zeroed (uniform softmax == reference row-mask)
  bf16x8 qf[2][2];
#pragma unroll
  for (int g = 0; g < 2; ++g) {
    const bool mq = (q0w + g * 16 + li) >= vl;
#pragma unroll
    for (int kk = 0; kk < 2; ++kk) {
      qf[g][kk] = *(const bf16x8*)(Qh + (size_t)(q0w + g * 16 + li) * HD + kk * 32 + lg * 8);
      if (mq) {
        union { u32 u[4]; bf16x8 v; } z; z.u[0] = z.u[1] = z.u[2] = z.u[3] = 0;
        qf[g][kk] = z.v;
      }
    }
  }

  // ones A-fragment (for l = ones * P MFMA)
  union { u16 h[8]; bf16x8 v; } onesU;
#pragma unroll
  for (int j = 0; j < 8; ++j) onesU.h[j] = 0x3F80;  // bf16 1.0
  const bf16x8 ones = onesU.v;

  // staging geometry: 8 x 1KB chunks per operand, 2 per wave; K gets sigma row
  // permute, both get chunk-XOR swizzle folded into the per-lane GLOBAL source
  int gq[2]; int kOff[2], vOff[2];
#pragma unroll
  for (int c = 0; c < 2; ++c) {
    gq[c] = w * 2 + c;
    const int s = gq[c] * 64 + l;      // 16B slot 0..511
    const int r = s >> 3, cs = s & 7;
    const int csrc = cs ^ (r & 7);
    const int sig = (r & 32) | (((r >> 2) & 3) << 3) | (((r >> 4) & 1) << 2) | (r & 3);
    kOff[c] = sig * HD + csrc * 8;
    vOff[c] = r * SQ + csrc * 8;
  }
  auto stageKV = [&](int buf, int kt) {
#pragma unroll
    for (int c = 0; c < 2; ++c) {
      gll16(Kh + (size_t)(kt * 64) * HD + kOff[c], &sK[buf][gq[c] * 512]);
      gll16(Vh + (size_t)(kt * 64) + vOff[c], &sV[buf][gq[c] * 512]);
    }
  };

  f32x4 z4 = {0.f, 0.f, 0.f, 0.f};
  f32x4 acc0[4], acc1[4], lacc0, lacc1;
#pragma unroll
  for (int ni = 0; ni < 4; ++ni) { acc0[ni] = z4; acc1[ni] = z4; }
  lacc0 = z4; lacc1 = z4;

  stageKV(0, 0);
  __syncthreads();
  int cur = 0;
  for (int kt = 0; kt < SQ / 64; ++kt) {
    if (kt + 1 < SQ / 64) stageKV(cur ^ 1, kt + 1);

    // S^T = K Q^T for both query groups (K frags shared)
    f32x4 sc0[4], sc1[4];
#pragma unroll
    for (int ni = 0; ni < 4; ++ni) {
      const int row = ni * 16 + li;
      bf16x8 kf0 = *(const bf16x8*)(&sK[cur][row * 64 + ((lg ^ (row & 7)) * 8)]);
      bf16x8 kf1 = *(const bf16x8*)(&sK[cur][row * 64 + (((4 + lg) ^ (row & 7)) * 8)]);
      sc0[ni] = __builtin_amdgcn_mfma_f32_16x16x32_bf16(kf0, qf[0][0], z4, 0, 0, 0);
      sc0[ni] = __builtin_amdgcn_mfma_f32_16x16x32_bf16(kf1, qf[0][1], sc0[ni], 0, 0, 0);
      sc1[ni] = __builtin_amdgcn_mfma_f32_16x16x32_bf16(kf0, qf[1][0], z4, 0, 0, 0);
      sc1[ni] = __builtin_amdgcn_mfma_f32_16x16x32_bf16(kf1, qf[1][1], sc1[ni], 0, 0, 0);
    }

    // fixed-anchor softmax: p = exp2(sc), packed straight into PV B-frags
    bf16x8 pb0[2], pb1[2];
#pragma unroll
    for (int h = 0; h < 2; ++h) {
      union { __bf16 e[8]; bf16x8 v; } A, B;
#pragma unroll
      for (int j = 0; j < 4; ++j) {
        A.e[j]     = (__bf16)__builtin_amdgcn_exp2f(sc0[2 * h][j]);
        A.e[4 + j] = (__bf16)__builtin_amdgcn_exp2f(sc0[2 * h + 1][j]);
        B.e[j]     = (__bf16)__builtin_amdgcn_exp2f(sc1[2 * h][j]);
        B.e[4 + j] = (__bf16)__builtin_amdgcn_exp2f(sc1[2 * h + 1][j]);
      }
      pb0[h] = A.v; pb1[h] = B.v;
    }

    // l += ones * P (matrix pipe; every lane gets its query's l in all 4 regs)
    lacc0 = __builtin_amdgcn_mfma_f32_16x16x32_bf16(ones, pb0[0], lacc0, 0, 0, 0);
    lacc0 = __builtin_amdgcn_mfma_f32_16x16x32_bf16(ones, pb0[1], lacc0, 0, 0, 0);
    lacc1 = __builtin_amdgcn_mfma_f32_16x16x32_bf16(ones, pb1[0], lacc1, 0, 0, 0);
    lacc1 = __builtin_amdgcn_mfma_f32_16x16x32_bf16(ones, pb1[1], lacc1, 0, 0, 0);

    // O^T += V^T P^T (V from LDS, staged last tile -> no same-tile stall)
#pragma unroll
    for (int ni = 0; ni < 4; ++ni) {
      const int row = ni * 16 + li;
      bf16x8 vf0 = *(const bf16x8*)(&sV[cur][row * 64 + ((lg ^ (row & 7)) * 8)]);
      bf16x8 vf1 = *(const bf16x8*)(&sV[cur][row * 64 + (((4 + lg) ^ (row & 7)) * 8)]);
      acc0[ni] = __builtin_amdgcn_mfma_f32_16x16x32_bf16(vf0, pb0[0], acc0[ni], 0, 0, 0);
      acc0[ni] = __builtin_amdgcn_mfma_f32_16x16x32_bf16(vf1, pb0[1], acc0[ni], 0, 0, 0);
      acc1[ni] = __builtin_amdgcn_mfma_f32_16x16x32_bf16(vf0, pb1[0], acc1[ni], 0, 0, 0);
      acc1[ni] = __builtin_amdgcn_mfma_f32_16x16x32_bf16(vf1, pb1[1], acc1[ni], 0, 0, 0);
    }

    __syncthreads();
    cur ^= 1;
  }

  // epilogue: normalize, write bf16 Ao (no cross-lane reduction needed)
  const int b = bh >> 4, h = bh & 15;
  const float lsum[2] = {lacc0[0], lacc1[0]};
#pragma unroll
  for (int g = 0; g < 2; ++g) {
    const float inv = 1.0f / lsum[g];
    f32x4* ac = g ? acc1 : acc0;
    const size_t rowb = ((size_t)(b * SQ + q0w + g * 16 + li)) * DM + h * HD;
#pragma unroll
    for (int ni = 0; ni < 4; ++ni) {
      union { __bf16 h2[4]; uint2 u; } ov;
#pragma unroll
      for (int r = 0; r < 4; ++r) ov.h2[r] = (__bf16)(ac[ni][r] * inv);
      *(uint2*)(Ao + rowb + ni * 16 + lg * 4) = ov.u;
    }
  }
}

extern "C" void kernel_launch(void* const* d_in, const int* in_sizes, int n_in,
                              void* d_out, int out_size, void* d_ws, size_t ws_size,
                              hipStream_t stream) {
  const float* X  = (const float*)d_in[0];
  const float* Wq = (const float*)d_in[1];
  const float* bq = (const float*)d_in[2];
  const float* Wk = (const float*)d_in[3];
  const float* bk = (const float*)d_in[4];
  const float* Wv = (const float*)d_in[5];
  const float* bv = (const float*)d_in[6];
  const float* Wo = (const float*)d_in[7];
  const float* bo = (const float*)d_in[8];
  const int* vlen = (const int*)d_in[9];

  char* ws = (char*)d_ws;
  u16* Qb  = (u16*)(ws);                       // 8 MB [32][2048][64]
  u16* Kb  = (u16*)(ws + (size_t)8388608);     // 8 MB
  u16* Vt  = (u16*)(ws + (size_t)16777216);    // 8 MB [32][64][2048]
  u16* Xb  = (u16*)(ws + (size_t)25165824);    // 8 MB [4096][1024] bf16
  u16* Ao  = Xb;                               // alias: Xb dead after qkv_gemm
  u16* Wqb = (u16*)(ws + (size_t)33554432);    // 2 MB each
  u16* Wkb = (u16*)(ws + (size_t)35651584);
  u16* Wvb = (u16*)(ws + (size_t)37748736);
  u16* Wob = (u16*)(ws + (size_t)39845888);    // ends at 40 MB

  dim3 blk(256);
  conv_bf16<<<4096, blk, 0, stream>>>(X, Wq, Wk, Wv, Wo, Xb, Wqb, Wkb, Wvb, Wob);
  qkv_gemm<<<dim3(8, 32, 3), blk, 0, stream>>>(Xb, Wqb, Wkb, Wvb, bq, bk, bv, Qb, Kb, Vt);
  attn_v8<<<dim3(32, 16), blk, 0, stream>>>(Qb, Kb, Vt, vlen, Ao);
  out_gemm<<<dim3(8, 32), blk, 0, stream>>>(Ao, Wob, bo, (float*)d_out);
}

// Round 9
// 118.306 us; speedup vs baseline: 1.7728x; 1.0795x over previous
//
#include <hip/hip_runtime.h>

#define SQ 2048
#define DM 1024
#define NH 16
#define HD 64

typedef __bf16 bf16x8 __attribute__((ext_vector_type(8)));
typedef float f32x4 __attribute__((ext_vector_type(4)));
typedef unsigned short u16;
typedef unsigned int u32;

// fp32 -> bf16 round-to-nearest-even (bulk convert pass)
__device__ __forceinline__ u16 f2b(float f) {
  union { float f; u32 u; } c; c.f = f;
  return (u16)((c.u + 0x7FFFu + ((c.u >> 16) & 1u)) >> 16);
}

// async global->LDS, 16B per lane; lds dest = wave-uniform base + lane*16
__device__ __forceinline__ void gll16(const void* g, void* l) {
  __builtin_amdgcn_global_load_lds(
      (const __attribute__((address_space(1))) void*)g,
      (__attribute__((address_space(3))) void*)l, 16, 0, 0);
}

// ---------------------------------------------------------------------------
// fp32 -> bf16 convert pass: X (4M elems) + Wq/Wk/Wv/Wo (1M each)
// Wq/Wk/Wv land contiguous -> usable as one 3072x1024 matrix.
// ---------------------------------------------------------------------------
__global__ void __launch_bounds__(256) conv_bf16(
    const float* __restrict__ X,
    const float* __restrict__ Wq, const float* __restrict__ Wk,
    const float* __restrict__ Wv, const float* __restrict__ Wo,
    u16* __restrict__ Xb, u16* __restrict__ Wqb, u16* __restrict__ Wkb,
    u16* __restrict__ Wvb, u16* __restrict__ Wob) {
  const size_t e = ((size_t)blockIdx.x * 256 + threadIdx.x) * 8;
  const float* src; u16* dst; size_t rel;
  if (e < 4194304u)      { src = X;  dst = Xb;  rel = e; }
  else if (e < 5242880u) { src = Wq; dst = Wqb; rel = e - 4194304u; }
  else if (e < 6291456u) { src = Wk; dst = Wkb; rel = e - 5242880u; }
  else if (e < 7340032u) { src = Wv; dst = Wvb; rel = e - 6291456u; }
  else                   { src = Wo; dst = Wob; rel = e - 7340032u; }
  float4 a = *(const float4*)(src + rel);
  float4 b = *(const float4*)(src + rel + 4);
  union { u16 h[8]; uint4 v; } o;
  o.h[0] = f2b(a.x); o.h[1] = f2b(a.y); o.h[2] = f2b(a.z); o.h[3] = f2b(a.w);
  o.h[4] = f2b(b.x); o.h[5] = f2b(b.y); o.h[6] = f2b(b.z); o.h[7] = f2b(b.w);
  *(uint4*)(dst + rel) = o.v;
}

// ---------------------------------------------------------------------------
// m97-style 128x128 NT GEMM core, bf16 inputs, BK=32, global_load_lds staging,
// double-buffered LDS ([2][128][32] linear per operand), 2-phase schedule.
// ---------------------------------------------------------------------------
__device__ __forceinline__ void stage128(const u16* __restrict__ A, const u16* __restrict__ B,
                                         u16* sA, u16* sB, int m0, int n0, int kt,
                                         int w, int l) {
#pragma unroll
  for (int c = 0; c < 2; ++c) {
    const int g = w * 2 + c;       // chunk-group 0..7 (1 KB each)
    const int s = g * 64 + l;      // 16B slot 0..511
    const int r = s >> 2, cc = s & 3;
    gll16(A + (size_t)(m0 + r) * DM + kt * 32 + cc * 8, sA + g * 512);
    gll16(B + (size_t)(n0 + r) * DM + kt * 32 + cc * 8, sB + g * 512);
  }
}

__device__ __forceinline__ void gemm_core2(const u16* __restrict__ A, const u16* __restrict__ B,
                                           u16* sA, u16* sB,   // each [2][4096] u16
                                           int m0, int n0, f32x4 acc[4][4]) {
  const int t = threadIdx.x, l = t & 63, w = t >> 6;
  const int wr = w >> 1, wc = w & 1, lg = l >> 4, li = l & 15;

  stage128(A, B, sA, sB, m0, n0, 0, w, l);
  __syncthreads();  // drains vmcnt(0) before barrier
  int cur = 0;
  for (int kt = 0; kt < DM / 32; ++kt) {
    if (kt + 1 < DM / 32)
      stage128(A, B, sA + (cur ^ 1) * 4096, sB + (cur ^ 1) * 4096, m0, n0, kt + 1, w, l);
    bf16x8 aF[4], bF[4];
#pragma unroll
    for (int mi = 0; mi < 4; ++mi)
      aF[mi] = *(const bf16x8*)(sA + cur * 4096 + (wr * 64 + mi * 16 + li) * 32 + lg * 8);
#pragma unroll
    for (int ni = 0; ni < 4; ++ni)
      bF[ni] = *(const bf16x8*)(sB + cur * 4096 + (wc * 64 + ni * 16 + li) * 32 + lg * 8);
#pragma unroll
    for (int mi = 0; mi < 4; ++mi)
#pragma unroll
      for (int ni = 0; ni < 4; ++ni)
        acc[mi][ni] = __builtin_amdgcn_mfma_f32_16x16x32_bf16(aF[mi], bF[ni], acc[mi][ni], 0, 0, 0);
    __syncthreads();
    cur ^= 1;
  }
}

// ---------------------------------------------------------------------------
// Merged QKV projection: one 4096x3072x1024 GEMM (Wqkv contiguous bf16).
// n in [0,1024): Q (scaled log2e/8); [1024,2048): K; [2048,3072): V^T.
// Grid (24,32) x-fastest: mode-interleaved dispatch + shared A-panel in L2.
// ---------------------------------------------------------------------------
__global__ void __launch_bounds__(256) qkv_gemm(
    const u16* __restrict__ Xb, const u16* __restrict__ Wqkv,
    const float* __restrict__ bq, const float* __restrict__ bk, const float* __restrict__ bv,
    u16* __restrict__ Qb, u16* __restrict__ Kb, u16* __restrict__ Vt) {
  __shared__ u16 sA[8192];
  __shared__ u16 sB[8192];
  const int m0 = blockIdx.y * 128, n0 = blockIdx.x * 128;
  const int mode = n0 >> 10;              // 0:Q 1:K 2:V (128 | 1024, block-uniform)
  const float* bias = (mode == 0) ? bq : (mode == 1) ? bk : bv;

  f32x4 acc[4][4];
  f32x4 z4 = {0.f, 0.f, 0.f, 0.f};
#pragma unroll
  for (int i = 0; i < 4; ++i)
#pragma unroll
    for (int j = 0; j < 4; ++j) acc[i][j] = z4;

  gemm_core2(Xb, Wqkv, sA, sB, m0, n0, acc);

  const int t = threadIdx.x;
  const int l = t & 63, w = t >> 6;
  const int wr = w >> 1, wc = w & 1, lg = l >> 4, li = l & 15;
#pragma unroll
  for (int mi = 0; mi < 4; ++mi) {
    const int m = m0 + wr * 64 + mi * 16 + lg * 4;
    const int b = m >> 11;           // batch
    const int s = m & 2047;          // seq pos
#pragma unroll
    for (int ni = 0; ni < 4; ++ni) {
      const int n = n0 + wc * 64 + ni * 16 + li;
      const int nn = n - (mode << 10);     // local col 0..1023
      const int h = nn >> 6, dd = nn & 63;
      const float bia = bias[nn];
      const size_t bh = (size_t)(b * NH + h);
      if (mode == 2) {
        // V^T: 4 consecutive seq positions for fixed dd -> one 8B store
        union { u16 h4[4]; uint2 u; } pk;
#pragma unroll
        for (int r = 0; r < 4; ++r) pk.h4[r] = f2b(acc[mi][ni][r] + bia);
        *(uint2*)(Vt + (bh * HD + dd) * SQ + s) = pk.u;
      } else {
#pragma unroll
        for (int r = 0; r < 4; ++r) {
          const float val = acc[mi][ni][r] + bia;
          const int ss = s + r;
          // Q prescale: (1/sqrt(HD)) * log2(e) so attn works in exp2 domain
          if (mode == 0) Qb[(bh * SQ + ss) * HD + dd] = f2b(val * 0.180336880f);
          else           Kb[(bh * SQ + ss) * HD + dd] = f2b(val);
        }
      }
    }
  }
}

// ---------------------------------------------------------------------------
// Final projection: out = Ao * Wo^T + bo (bf16 in, fp32 out).
// 64x128 tile, grid (8,64) = 512 blocks = 2 blocks/CU (was 256 = 1/CU).
// 4 waves as 2Mx2N (each 32x64 = 2x4 frags, 8 MFMA/kt), BK=32 dbuf.
// ---------------------------------------------------------------------------
__global__ void __launch_bounds__(256) out_gemm(
    const u16* __restrict__ Ag, const u16* __restrict__ Wob,
    const float* __restrict__ bo, float* __restrict__ out) {
  __shared__ u16 sA[2][2048];   // [64][32] u16 per buf (4KB)
  __shared__ u16 sB[2][4096];   // [128][32] u16 per buf (8KB)
  const int t = threadIdx.x, l = t & 63, w = t >> 6;
  const int wr = w >> 1, wc = w & 1, lg = l >> 4, li = l & 15;
  const int m0 = blockIdx.y * 64, n0 = blockIdx.x * 128;

  // staging: A = 4 chunks (1 per wave), B = 8 chunks (2 per wave)
  auto stage = [&](int buf, int kt) {
    {
      const int s = w * 64 + l;          // A slot 0..255
      const int r = s >> 2, cc = s & 3;
      gll16(Ag + (size_t)(m0 + r) * DM + kt * 32 + cc * 8, &sA[buf][w * 512]);
    }
#pragma unroll
    for (int c = 0; c < 2; ++c) {
      const int g = w * 2 + c;           // B chunk 0..7
      const int s = g * 64 + l;          // B slot 0..511
      const int r = s >> 2, cc = s & 3;
      gll16(Wob + (size_t)(n0 + r) * DM + kt * 32 + cc * 8, &sB[buf][g * 512]);
    }
  };

  f32x4 acc[2][4];
  f32x4 z4 = {0.f, 0.f, 0.f, 0.f};
#pragma unroll
  for (int i = 0; i < 2; ++i)
#pragma unroll
    for (int j = 0; j < 4; ++j) acc[i][j] = z4;

  stage(0, 0);
  __syncthreads();
  int cur = 0;
  for (int kt = 0; kt < DM / 32; ++kt) {
    if (kt + 1 < DM / 32) stage(cur ^ 1, kt + 1);
    bf16x8 aF[2], bF[4];
#pragma unroll
    for (int mi = 0; mi < 2; ++mi)
      aF[mi] = *(const bf16x8*)(&sA[cur][(wr * 32 + mi * 16 + li) * 32 + lg * 8]);
#pragma unroll
    for (int ni = 0; ni < 4; ++ni)
      bF[ni] = *(const bf16x8*)(&sB[cur][(wc * 64 + ni * 16 + li) * 32 + lg * 8]);
#pragma unroll
    for (int mi = 0; mi < 2; ++mi)
#pragma unroll
      for (int ni = 0; ni < 4; ++ni)
        acc[mi][ni] = __builtin_amdgcn_mfma_f32_16x16x32_bf16(aF[mi], bF[ni], acc[mi][ni], 0, 0, 0);
    __syncthreads();
    cur ^= 1;
  }

#pragma unroll
  for (int mi = 0; mi < 2; ++mi) {
    const int m = m0 + wr * 32 + mi * 16 + lg * 4;
#pragma unroll
    for (int ni = 0; ni < 4; ++ni) {
      const int n = n0 + wc * 64 + ni * 16 + li;
      const float bia = bo[n];
#pragma unroll
      for (int r = 0; r < 4; ++r)
        out[(size_t)(m + r) * DM + n] = acc[mi][ni][r] + bia;
    }
  }
}

// ---------------------------------------------------------------------------
// Flash attention v8 (unchanged from R7 — proven 0-conflict, ~48us):
//  - 4 waves x 32 queries, K sigma-staged + V^T staged, both gll16 dbuf
//  - zero-shuffle P->PV; fixed-anchor exp2 softmax; masked queries via qf=0
//  - l via ones-MFMA; bh-fastest grid pins 4 heads' K/V per XCD L2
// ---------------------------------------------------------------------------
__global__ void __launch_bounds__(256) attn_v8(
    const u16* __restrict__ Qb, const u16* __restrict__ Kb, const u16* __restrict__ Vt,
    const int* __restrict__ vlen, u16* __restrict__ Ao) {
  __shared__ u16 sK[2][4096];   // [64 keys(sigma)][64 dk], chunk-XOR swizzled
  __shared__ u16 sV[2][4096];   // [64 d][64 keys(natural)], chunk-XOR swizzled
  const int bh = blockIdx.x, qt = blockIdx.y;
  const int t = threadIdx.x, w = t >> 6, l = t & 63, lg = l >> 4, li = l & 15;
  const int vl = vlen[bh];
  const u16* Qh = Qb + (size_t)bh * SQ * HD;
  const u16* Kh = Kb + (size_t)bh * SQ * HD;
  const u16* Vh = Vt + (size_t)bh * HD * SQ;
  const int q0w = qt * 128 + w * 32;      // wave's 32 queries: q0w + g*16 + li

  bf16x8 qf[2][2];
#pragma unroll
  for (int g = 0; g < 2; ++g) {
    const bool mq = (q0w + g * 16 + li) >= vl;
#pragma unroll
    for (int kk = 0; kk < 2; ++kk) {
      qf[g][kk] = *(const bf16x8*)(Qh + (size_t)(q0w + g * 16 + li) * HD + kk * 32 + lg * 8);
      if (mq) {
        union { u32 u[4]; bf16x8 v; } z; z.u[0] = z.u[1] = z.u[2] = z.u[3] = 0;
        qf[g][kk] = z.v;
      }
    }
  }

  union { u16 h[8]; bf16x8 v; } onesU;
#pragma unroll
  for (int j = 0; j < 8; ++j) onesU.h[j] = 0x3F80;  // bf16 1.0
  const bf16x8 ones = onesU.v;

  int gq[2]; int kOff[2], vOff[2];
#pragma unroll
  for (int c = 0; c < 2; ++c) {
    gq[c] = w * 2 + c;
    const int s = gq[c] * 64 + l;      // 16B slot 0..511
    const int r = s >> 3, cs = s & 7;
    const int csrc = cs ^ (r & 7);
    const int sig = (r & 32) | (((r >> 2) & 3) << 3) | (((r >> 4) & 1) << 2) | (r & 3);
    kOff[c] = sig * HD + csrc * 8;
    vOff[c] = r * SQ + csrc * 8;
  }
  auto stageKV = [&](int buf, int kt) {
#pragma unroll
    for (int c = 0; c < 2; ++c) {
      gll16(Kh + (size_t)(kt * 64) * HD + kOff[c], &sK[buf][gq[c] * 512]);
      gll16(Vh + (size_t)(kt * 64) + vOff[c], &sV[buf][gq[c] * 512]);
    }
  };

  f32x4 z4 = {0.f, 0.f, 0.f, 0.f};
  f32x4 acc0[4], acc1[4], lacc0, lacc1;
#pragma unroll
  for (int ni = 0; ni < 4; ++ni) { acc0[ni] = z4; acc1[ni] = z4; }
  lacc0 = z4; lacc1 = z4;

  stageKV(0, 0);
  __syncthreads();
  int cur = 0;
  for (int kt = 0; kt < SQ / 64; ++kt) {
    if (kt + 1 < SQ / 64) stageKV(cur ^ 1, kt + 1);

    f32x4 sc0[4], sc1[4];
#pragma unroll
    for (int ni = 0; ni < 4; ++ni) {
      const int row = ni * 16 + li;
      bf16x8 kf0 = *(const bf16x8*)(&sK[cur][row * 64 + ((lg ^ (row & 7)) * 8)]);
      bf16x8 kf1 = *(const bf16x8*)(&sK[cur][row * 64 + (((4 + lg) ^ (row & 7)) * 8)]);
      sc0[ni] = __builtin_amdgcn_mfma_f32_16x16x32_bf16(kf0, qf[0][0], z4, 0, 0, 0);
      sc0[ni] = __builtin_amdgcn_mfma_f32_16x16x32_bf16(kf1, qf[0][1], sc0[ni], 0, 0, 0);
      sc1[ni] = __builtin_amdgcn_mfma_f32_16x16x32_bf16(kf0, qf[1][0], z4, 0, 0, 0);
      sc1[ni] = __builtin_amdgcn_mfma_f32_16x16x32_bf16(kf1, qf[1][1], sc1[ni], 0, 0, 0);
    }

    bf16x8 pb0[2], pb1[2];
#pragma unroll
    for (int h = 0; h < 2; ++h) {
      union { __bf16 e[8]; bf16x8 v; } A, B;
#pragma unroll
      for (int j = 0; j < 4; ++j) {
        A.e[j]     = (__bf16)__builtin_amdgcn_exp2f(sc0[2 * h][j]);
        A.e[4 + j] = (__bf16)__builtin_amdgcn_exp2f(sc0[2 * h + 1][j]);
        B.e[j]     = (__bf16)__builtin_amdgcn_exp2f(sc1[2 * h][j]);
        B.e[4 + j] = (__bf16)__builtin_amdgcn_exp2f(sc1[2 * h + 1][j]);
      }
      pb0[h] = A.v; pb1[h] = B.v;
    }

    lacc0 = __builtin_amdgcn_mfma_f32_16x16x32_bf16(ones, pb0[0], lacc0, 0, 0, 0);
    lacc0 = __builtin_amdgcn_mfma_f32_16x16x32_bf16(ones, pb0[1], lacc0, 0, 0, 0);
    lacc1 = __builtin_amdgcn_mfma_f32_16x16x32_bf16(ones, pb1[0], lacc1, 0, 0, 0);
    lacc1 = __builtin_amdgcn_mfma_f32_16x16x32_bf16(ones, pb1[1], lacc1, 0, 0, 0);

#pragma unroll
    for (int ni = 0; ni < 4; ++ni) {
      const int row = ni * 16 + li;
      bf16x8 vf0 = *(const bf16x8*)(&sV[cur][row * 64 + ((lg ^ (row & 7)) * 8)]);
      bf16x8 vf1 = *(const bf16x8*)(&sV[cur][row * 64 + (((4 + lg) ^ (row & 7)) * 8)]);
      acc0[ni] = __builtin_amdgcn_mfma_f32_16x16x32_bf16(vf0, pb0[0], acc0[ni], 0, 0, 0);
      acc0[ni] = __builtin_amdgcn_mfma_f32_16x16x32_bf16(vf1, pb0[1], acc0[ni], 0, 0, 0);
      acc1[ni] = __builtin_amdgcn_mfma_f32_16x16x32_bf16(vf0, pb1[0], acc1[ni], 0, 0, 0);
      acc1[ni] = __builtin_amdgcn_mfma_f32_16x16x32_bf16(vf1, pb1[1], acc1[ni], 0, 0, 0);
    }

    __syncthreads();
    cur ^= 1;
  }

  const int b = bh >> 4, h = bh & 15;
  const float lsum[2] = {lacc0[0], lacc1[0]};
#pragma unroll
  for (int g = 0; g < 2; ++g) {
    const float inv = 1.0f / lsum[g];
    f32x4* ac = g ? acc1 : acc0;
    const size_t rowb = ((size_t)(b * SQ + q0w + g * 16 + li)) * DM + h * HD;
#pragma unroll
    for (int ni = 0; ni < 4; ++ni) {
      union { __bf16 h2[4]; uint2 u; } ov;
#pragma unroll
      for (int r = 0; r < 4; ++r) ov.h2[r] = (__bf16)(ac[ni][r] * inv);
      *(uint2*)(Ao + rowb + ni * 16 + lg * 4) = ov.u;
    }
  }
}

extern "C" void kernel_launch(void* const* d_in, const int* in_sizes, int n_in,
                              void* d_out, int out_size, void* d_ws, size_t ws_size,
                              hipStream_t stream) {
  const float* X  = (const float*)d_in[0];
  const float* Wq = (const float*)d_in[1];
  const float* bq = (const float*)d_in[2];
  const float* Wk = (const float*)d_in[3];
  const float* bk = (const float*)d_in[4];
  const float* Wv = (const float*)d_in[5];
  const float* bv = (const float*)d_in[6];
  const float* Wo = (const float*)d_in[7];
  const float* bo = (const float*)d_in[8];
  const int* vlen = (const int*)d_in[9];

  char* ws = (char*)d_ws;
  u16* Qb  = (u16*)(ws);                       // 8 MB [32][2048][64]
  u16* Kb  = (u16*)(ws + (size_t)8388608);     // 8 MB
  u16* Vt  = (u16*)(ws + (size_t)16777216);    // 8 MB [32][64][2048]
  u16* Xb  = (u16*)(ws + (size_t)25165824);    // 8 MB [4096][1024] bf16
  u16* Ao  = Xb;                               // alias: Xb dead after qkv_gemm
  u16* Wqb = (u16*)(ws + (size_t)33554432);    // 2 MB each; Wq/Wk/Wv contiguous
  u16* Wkb = (u16*)(ws + (size_t)35651584);
  u16* Wvb = (u16*)(ws + (size_t)37748736);
  u16* Wob = (u16*)(ws + (size_t)39845888);    // ends at 40 MB

  dim3 blk(256);
  conv_bf16<<<4096, blk, 0, stream>>>(X, Wq, Wk, Wv, Wo, Xb, Wqb, Wkb, Wvb, Wob);
  qkv_gemm<<<dim3(24, 32), blk, 0, stream>>>(Xb, Wqb, bq, bk, bv, Qb, Kb, Vt);
  attn_v8<<<dim3(32, 16), blk, 0, stream>>>(Qb, Kb, Vt, vlen, Ao);
  out_gemm<<<dim3(8, 64), blk, 0, stream>>>(Ao, Wob, bo, (float*)d_out);
}